// Round 12
// baseline (1254.637 us; speedup 1.0000x reference)
//
#include <hip/hip_runtime.h>
#include <cstdint>
#include <cstddef>

#define NLAYERS 3
#define NN      512
#define DIN     4
#define MTILE   64            // batch rows per workgroup
#define KAUG    544           // 512 (H/T) + 4 (X) + 1 (bias one) + 27 zero pad
#define LDA     552           // LDS row stride in bf16 elems
#define WELEMS  (NN * KAUG)   // one prepared weight matrix, bf16 elems
#define LDS_BYTES (2 * MTILE * LDA * 2)
#define NTHREADS 1024         // 16 waves: one 32-col block per wave -> 4 waves/SIMD

typedef __attribute__((ext_vector_type(8))) short short8;   // 8 x bf16 (4 VGPRs)
typedef __attribute__((ext_vector_type(4))) float f32x4;    // MFMA accumulator

__device__ __forceinline__ short f2bf(float f) {
    union { float f; uint32_t u; } v; v.f = f;
    uint32_t r = v.u + 0x7fffu + ((v.u >> 16) & 1u);   // RNE
    return (short)(r >> 16);
}
// pack two f32 -> two bf16 (RNE) in one VALU instr; bit-identical to f2bf pair.
__device__ __forceinline__ uint32_t f2bf_pk(float lo, float hi) {
    uint32_t r;
    asm("v_cvt_pk_bf16_f32 %0, %1, %2" : "=v"(r) : "v"(lo), "v"(hi));
    return r;
}
__device__ __forceinline__ float bf2f(short s) {
    union { uint32_t u; float f; } v; v.u = ((uint32_t)(uint16_t)s) << 16;
    return v.f;
}
__device__ __forceinline__ float sig_(float x)  { return 1.0f / (1.0f + __expf(-x)); }
__device__ __forceinline__ float tanh_(float x) { return 1.0f - 2.0f / (1.0f + __expf(2.0f * x)); }
__device__ __forceinline__ float silu_(float x) { return x / (1.0f + __expf(-x)); }

#define MFMA_BF16 __builtin_amdgcn_mfma_f32_16x16x32_bf16

// ---------------- prep: 12 transposed + augmented bf16 weight matrices in ws ------------
// mat m = layer*4 + {0:F,1:U,2:O1,3:O2}; Bt[n][kk]:
//   kk<512 -> U[kk][n]; 512..515 -> W[kk-512][n] (0 for O2); 516 -> bias[n]; else 0.
__global__ void prep_kernel(const float* __restrict__ Wf,  const float* __restrict__ Uf,  const float* __restrict__ bf,
                            const float* __restrict__ Wu,  const float* __restrict__ Uu,  const float* __restrict__ bu,
                            const float* __restrict__ Wo1, const float* __restrict__ Uo1, const float* __restrict__ bo1,
                            const float* __restrict__ Wo2, const float* __restrict__ bo2,
                            short* __restrict__ ws) {
    int idx = blockIdx.x * 256 + threadIdx.x;
    int m   = idx / WELEMS;
    if (m >= 12) return;
    int rem = idx - m * WELEMS;
    int n   = rem / KAUG;
    int kk  = rem - n * KAUG;
    int layer = m >> 2, t = m & 3;
    const float* U; const float* W; const float* b;
    switch (t) {
        case 0:  U = Uf;  W = Wf;      b = bf;  break;
        case 1:  U = Uu;  W = Wu;      b = bu;  break;
        case 2:  U = Uo1; W = Wo1;     b = bo1; break;
        default: U = Wo2; W = nullptr; b = bo2; break;
    }
    float val = 0.0f;
    if (kk < NN)             val = U[layer * NN * NN + kk * NN + n];
    else if (kk < NN + DIN)  val = W ? W[layer * DIN * NN + (kk - NN) * NN + n] : 0.0f;
    else if (kk == NN + DIN) val = b[layer * NN + n];
    ws[idx] = f2bf(val);
}

// 64x32 @ K=544 MFMA block: A from LDS, Bt from global.
// A: ROTATING single set — a[mt] reloaded immediately after its 2 MFMAs in half h,
//    consumed at the same position in half h+1 -> 8-MFMA issue-to-consume slack
//    (identical to the d1 ping-pong) at HALF the registers (16 vs 32).
// B: distance-4 ring (b0..b3) — each B fragment issued 32 MFMAs (~620+ cyc) before
//    use. 2x the in-flight B bytes vs d2: the kernel is B-delivery-limited (52 B/cyc
//    L2 demand at the MFMA floor vs ~18 B/cyc achieved at d2; R3's spilled d4 matched
//    d2 DESPITE 437 MB scratch traffic -> depth gains were real, registers were the box).
// Register audit (the R3/R8/R11 lesson): A 16 + B 32 + addr ~12 = ~60 <= 64 arch
// VGPRs at 4 waves/SIMD; acc 32 in AGPR. Gate on WRITE_SIZE < 2 MB.
// 17 K-halves: prologue(4-deep B) + 3 x 4-half iters (0..11) + 5-half static tail.
__device__ __forceinline__ void mm1(const short* __restrict__ Asrc, const short* __restrict__ Bt,
                                    int n0, int l16, int quad, f32x4 (&acc)[4][2]) {
#pragma unroll
    for (int mt = 0; mt < 4; ++mt)
#pragma unroll
        for (int nt = 0; nt < 2; ++nt) acc[mt][nt] = f32x4{0.f, 0.f, 0.f, 0.f};
    const short* aP = Asrc + l16 * LDA + quad * 8;
    const short* bP = Bt + (size_t)(n0 + l16) * KAUG + quad * 8;

    short8 a[4];
    short8 b0[2], b1[2], b2[2], b3[2];

#pragma unroll
    for (int mt = 0; mt < 4; ++mt) a[mt] = *(const short8*)(aP + mt * 16 * LDA);   // A[0]
#pragma unroll
    for (int nt = 0; nt < 2; ++nt) {
        b0[nt] = *(const short8*)(bP + nt * 16 * KAUG);        // B[0]
        b1[nt] = *(const short8*)(bP + nt * 16 * KAUG + 32);   // B[1]
        b2[nt] = *(const short8*)(bP + nt * 16 * KAUG + 64);   // B[2]
        b3[nt] = *(const short8*)(bP + nt * 16 * KAUG + 96);   // B[3]
    }

#pragma unroll 1
    for (int i = 0; i < 3; ++i) {          // halves 4i .. 4i+3  (0..11)
        // h = 4i: consume b0; a[mt] rotates to A[4i+1] right after its 2 MFMAs
#pragma unroll
        for (int mt = 0; mt < 4; ++mt) {
            acc[mt][0] = MFMA_BF16(a[mt], b0[0], acc[mt][0], 0, 0, 0);
            acc[mt][1] = MFMA_BF16(a[mt], b0[1], acc[mt][1], 0, 0, 0);
            a[mt] = *(const short8*)(aP + mt * 16 * LDA + 32);
        }
#pragma unroll
        for (int nt = 0; nt < 2; ++nt) b0[nt] = *(const short8*)(bP + nt * 16 * KAUG + 128); // B[4i+4]
        // h = 4i+1
#pragma unroll
        for (int mt = 0; mt < 4; ++mt) {
            acc[mt][0] = MFMA_BF16(a[mt], b1[0], acc[mt][0], 0, 0, 0);
            acc[mt][1] = MFMA_BF16(a[mt], b1[1], acc[mt][1], 0, 0, 0);
            a[mt] = *(const short8*)(aP + mt * 16 * LDA + 64);
        }
#pragma unroll
        for (int nt = 0; nt < 2; ++nt) b1[nt] = *(const short8*)(bP + nt * 16 * KAUG + 160); // B[4i+5]
        // h = 4i+2
#pragma unroll
        for (int mt = 0; mt < 4; ++mt) {
            acc[mt][0] = MFMA_BF16(a[mt], b2[0], acc[mt][0], 0, 0, 0);
            acc[mt][1] = MFMA_BF16(a[mt], b2[1], acc[mt][1], 0, 0, 0);
            a[mt] = *(const short8*)(aP + mt * 16 * LDA + 96);
        }
#pragma unroll
        for (int nt = 0; nt < 2; ++nt) b2[nt] = *(const short8*)(bP + nt * 16 * KAUG + 192); // B[4i+6]
        // h = 4i+3
#pragma unroll
        for (int mt = 0; mt < 4; ++mt) {
            acc[mt][0] = MFMA_BF16(a[mt], b3[0], acc[mt][0], 0, 0, 0);
            acc[mt][1] = MFMA_BF16(a[mt], b3[1], acc[mt][1], 0, 0, 0);
            a[mt] = *(const short8*)(aP + mt * 16 * LDA + 128);
        }
#pragma unroll
        for (int nt = 0; nt < 2; ++nt) b3[nt] = *(const short8*)(bP + nt * 16 * KAUG + 224); // B[4i+7]
        aP += 128; bP += 128;
    }
    // tail: halves 12..16. Here a = A[12], b0..b3 = B[12..15]; bases at half-12.
#pragma unroll
    for (int mt = 0; mt < 4; ++mt) {
        acc[mt][0] = MFMA_BF16(a[mt], b0[0], acc[mt][0], 0, 0, 0);   // h12
        acc[mt][1] = MFMA_BF16(a[mt], b0[1], acc[mt][1], 0, 0, 0);
        a[mt] = *(const short8*)(aP + mt * 16 * LDA + 32);           // A[13]
    }
#pragma unroll
    for (int nt = 0; nt < 2; ++nt) b0[nt] = *(const short8*)(bP + nt * 16 * KAUG + 128);     // B[16]
#pragma unroll
    for (int mt = 0; mt < 4; ++mt) {
        acc[mt][0] = MFMA_BF16(a[mt], b1[0], acc[mt][0], 0, 0, 0);   // h13
        acc[mt][1] = MFMA_BF16(a[mt], b1[1], acc[mt][1], 0, 0, 0);
        a[mt] = *(const short8*)(aP + mt * 16 * LDA + 64);           // A[14]
    }
#pragma unroll
    for (int mt = 0; mt < 4; ++mt) {
        acc[mt][0] = MFMA_BF16(a[mt], b2[0], acc[mt][0], 0, 0, 0);   // h14
        acc[mt][1] = MFMA_BF16(a[mt], b2[1], acc[mt][1], 0, 0, 0);
        a[mt] = *(const short8*)(aP + mt * 16 * LDA + 96);           // A[15]
    }
#pragma unroll
    for (int mt = 0; mt < 4; ++mt) {
        acc[mt][0] = MFMA_BF16(a[mt], b3[0], acc[mt][0], 0, 0, 0);   // h15
        acc[mt][1] = MFMA_BF16(a[mt], b3[1], acc[mt][1], 0, 0, 0);
        a[mt] = *(const short8*)(aP + mt * 16 * LDA + 128);          // A[16]
    }
#pragma unroll
    for (int mt = 0; mt < 4; ++mt) {
        acc[mt][0] = MFMA_BF16(a[mt], b0[0], acc[mt][0], 0, 0, 0);   // h16
        acc[mt][1] = MFMA_BF16(a[mt], b0[1], acc[mt][1], 0, 0, 0);
    }
}

// ---------------- fused DGM kernel: one 16-wave workgroup = 64 batch rows ----------------
__global__ void __launch_bounds__(NTHREADS, 4)
dgm_kernel(const float* __restrict__ X, const float* __restrict__ W_in, const float* __restrict__ b_in,
           const float* __restrict__ W_out, const float* __restrict__ b_out,
           const short* __restrict__ wmats, float* __restrict__ out) {
    extern __shared__ short lds[];
    short* Hb = lds;                 // [MTILE][LDA]  bf16, cols 512..516 = [X|1]
    short* Tb = lds + MTILE * LDA;   // [MTILE][LDA]  bf16, same augmentation (0,0,0,0,1)

    const int tid  = threadIdx.x;
    const int lane = tid & 63;
    const int wv   = tid >> 6;       // wave 0..15
    const int l16  = lane & 15;
    const int quad = lane >> 4;
    const int n0   = wv * 32;        // this wave's 32-column block
    const int rbase = blockIdx.x * MTILE;

    // ---- H = silu(X @ W_in + b_in): column fixed per thread -> hoist W_in/b_in loads ----
    {
        const int cfix = tid & (NN - 1);
        const int rstart = tid >> 9;             // 0 or 1; rows advance by 2 per j
        const float w0 = W_in[0 * NN + cfix];
        const float w1 = W_in[1 * NN + cfix];
        const float w2 = W_in[2 * NN + cfix];
        const float w3 = W_in[3 * NN + cfix];
        const float bc = b_in[cfix];
#pragma unroll 4
        for (int j = 0; j < (MTILE * NN) / NTHREADS; ++j) {
            int r = rstart + j * (NTHREADS / NN);
            const float4 x = *(const float4*)(X + (size_t)(rbase + r) * DIN);
            float v = bc + x.x * w0 + x.y * w1 + x.z * w2 + x.w * w3;
            Hb[r * LDA + cfix] = f2bf(silu_(v));
        }
    }
    if (tid < MTILE) {
        int r = tid;
        const float* xr = X + (size_t)(rbase + r) * DIN;
#pragma unroll
        for (int k = 0; k < DIN; ++k) {
            Hb[r * LDA + NN + k] = f2bf(xr[k]);
            Tb[r * LDA + NN + k] = 0;
        }
        Hb[r * LDA + NN + DIN] = f2bf(1.0f);
        Tb[r * LDA + NN + DIN] = f2bf(1.0f);
        for (int k = NN + DIN + 1; k < KAUG; ++k) {
            Hb[r * LDA + k] = 0;
            Tb[r * LDA + k] = 0;
        }
    }
    __syncthreads();

    uint32_t Fpack[16];   // sigmoid(F) for this wave's 64x32 tile, packed bf16 pairs

    for (int layer = 0; layer < NLAYERS; ++layer) {
        const short* wF  = wmats + (size_t)(layer * 4 + 0) * WELEMS;
        const short* wU  = wmats + (size_t)(layer * 4 + 1) * WELEMS;
        const short* wO1 = wmats + (size_t)(layer * 4 + 2) * WELEMS;
        const short* wO2 = wmats + (size_t)(layer * 4 + 3) * WELEMS;

        // ---- Phase A: T = sigmoid(pre_U)*tanh(pre_O1) -> Tb; F kept packed in regs ----
        uint32_t Tpack[16];
        {
            f32x4 aO[4][2];
            mm1(Hb, wO1, n0, l16, quad, aO);
#pragma unroll
            for (int mt = 0; mt < 4; ++mt)
#pragma unroll
                for (int nt = 0; nt < 2; ++nt)
#pragma unroll
                    for (int rp = 0; rp < 2; ++rp)
                        Tpack[mt * 4 + nt * 2 + rp] =
                            f2bf_pk(tanh_(aO[mt][nt][2 * rp + 0]), tanh_(aO[mt][nt][2 * rp + 1]));
        }
        {
            f32x4 aU[4][2];
            mm1(Hb, wU, n0, l16, quad, aU);
#pragma unroll
            for (int mt = 0; mt < 4; ++mt)
#pragma unroll
                for (int nt = 0; nt < 2; ++nt)
#pragma unroll
                    for (int rp = 0; rp < 2; ++rp) {
                        uint32_t tp = Tpack[mt * 4 + nt * 2 + rp];
                        float to0 = bf2f((short)(uint16_t)(tp & 0xffffu));
                        float to1 = bf2f((short)(uint16_t)(tp >> 16));
                        float t0 = sig_(aU[mt][nt][2 * rp + 0]) * to0;
                        float t1 = sig_(aU[mt][nt][2 * rp + 1]) * to1;
                        uint32_t pk = f2bf_pk(t0, t1);
                        int row = mt * 16 + quad * 4 + 2 * rp;
                        int col = n0 + nt * 16 + l16;
                        Tb[row * LDA + col]       = (short)(uint16_t)(pk & 0xffffu);
                        Tb[(row + 1) * LDA + col] = (short)(uint16_t)(pk >> 16);
                    }
        }
        {
            f32x4 aF[4][2];
            mm1(Hb, wF, n0, l16, quad, aF);
#pragma unroll
            for (int mt = 0; mt < 4; ++mt)
#pragma unroll
                for (int nt = 0; nt < 2; ++nt)
#pragma unroll
                    for (int rp = 0; rp < 2; ++rp)
                        Fpack[mt * 4 + nt * 2 + rp] =
                            f2bf_pk(sig_(aF[mt][nt][2 * rp + 0]), sig_(aF[mt][nt][2 * rp + 1]));
        }
        __syncthreads();   // Tb complete everywhere; Hb reads as A-operand done

        // ---- Phase B: O2 = silu(T @ Wo2 + bo2); H = F*H + O2 (own tile only) ----
        {
            f32x4 aO2[4][2];
            mm1(Tb, wO2, n0, l16, quad, aO2);
#pragma unroll
            for (int mt = 0; mt < 4; ++mt)
#pragma unroll
                for (int nt = 0; nt < 2; ++nt)
#pragma unroll
                    for (int rp = 0; rp < 2; ++rp) {
                        uint32_t fp = Fpack[mt * 4 + nt * 2 + rp];
                        float f0 = bf2f((short)(uint16_t)(fp & 0xffffu));
                        float f1 = bf2f((short)(uint16_t)(fp >> 16));
                        int row = mt * 16 + quad * 4 + 2 * rp;
                        int col = n0 + nt * 16 + l16;
                        float h0 = bf2f(Hb[row * LDA + col]);
                        float h1 = bf2f(Hb[(row + 1) * LDA + col]);
                        float n0v = f0 * h0 + silu_(aO2[mt][nt][2 * rp + 0]);
                        float n1v = f1 * h1 + silu_(aO2[mt][nt][2 * rp + 1]);
                        uint32_t pk = f2bf_pk(n0v, n1v);
                        Hb[row * LDA + col]       = (short)(uint16_t)(pk & 0xffffu);
                        Hb[(row + 1) * LDA + col] = (short)(uint16_t)(pk >> 16);
                    }
        }
        __syncthreads();   // Hb fully updated before next layer reads all of it
    }

    // ---- out = silu(H @ W_out + b_out): b128 LDS reads (aligned: LDA*2=1104=69*16) ----
    {
        const int r = tid >> 4, q = tid & 15;
        const int c0 = q * (NN / 16);
        const short8* hp = (const short8*)(Hb + r * LDA + c0);
        float p = 0.0f;
#pragma unroll
        for (int v = 0; v < (NN / 16) / 8; ++v) {
            short8 h = hp[v];
#pragma unroll
            for (int e = 0; e < 8; ++e)
                p += bf2f(h[e]) * W_out[c0 + v * 8 + e];
        }
        float* red = (float*)Tb;     // Tb is free now
        red[tid] = p;
        __syncthreads();
        if (q == 0) {
            float s = b_out[0];
#pragma unroll
            for (int i = 0; i < 16; ++i) s += red[r * 16 + i];
            out[rbase + r] = silu_(s);
        }
    }
}

extern "C" void kernel_launch(void* const* d_in, const int* in_sizes, int n_in,
                              void* d_out, int out_size, void* d_ws, size_t ws_size,
                              hipStream_t stream) {
    const float* X     = (const float*)d_in[0];
    const float* W_in  = (const float*)d_in[1];
    const float* b_in  = (const float*)d_in[2];
    const float* Wf    = (const float*)d_in[3];
    const float* Uf    = (const float*)d_in[4];
    const float* bf    = (const float*)d_in[5];
    const float* Wu    = (const float*)d_in[6];
    const float* Uu    = (const float*)d_in[7];
    const float* bu    = (const float*)d_in[8];
    const float* Wo1   = (const float*)d_in[9];
    const float* Uo1   = (const float*)d_in[10];
    const float* bo1   = (const float*)d_in[11];
    const float* Wo2   = (const float*)d_in[12];
    const float* bo2   = (const float*)d_in[13];
    const float* W_out = (const float*)d_in[14];
    const float* b_out = (const float*)d_in[15];
    float* out = (float*)d_out;
    short* ws  = (short*)d_ws;       // needs 12*512*544*2 = 6.7 MB

    const int B = in_sizes[0] / DIN;

    prep_kernel<<<(12 * WELEMS + 255) / 256, 256, 0, stream>>>(
        Wf, Uf, bf, Wu, Uu, bu, Wo1, Uo1, bo1, Wo2, bo2, ws);

    hipFuncSetAttribute((const void*)dgm_kernel,
                        hipFuncAttributeMaxDynamicSharedMemorySize, LDS_BYTES);
    dgm_kernel<<<B / MTILE, NTHREADS, LDS_BYTES, stream>>>(X, W_in, b_in, W_out, b_out, ws, out);
}

// Round 14
// 1196.618 us; speedup vs baseline: 1.0485x; 1.0485x over previous
//
#include <hip/hip_runtime.h>
#include <cstdint>
#include <cstddef>

#define NLAYERS 3
#define NN      512
#define DIN     4
#define MTILE   64            // batch rows per workgroup
#define KAUG    544           // 512 (H/T) + 4 (X) + 1 (bias one) + 27 zero pad
#define LDA     552           // LDS row stride in bf16 elems
#define WELEMS  (NN * KAUG)   // one prepared weight matrix, bf16 elems
#define LDS_BYTES (2 * MTILE * LDA * 2)
#define NTHREADS 1024         // 16 waves: one 32-col block per wave -> 4 waves/SIMD

typedef __attribute__((ext_vector_type(8))) short short8;   // 8 x bf16 (4 VGPRs)
typedef __attribute__((ext_vector_type(4))) float f32x4;    // MFMA accumulator

__device__ __forceinline__ short f2bf(float f) {
    union { float f; uint32_t u; } v; v.f = f;
    uint32_t r = v.u + 0x7fffu + ((v.u >> 16) & 1u);   // RNE
    return (short)(r >> 16);
}
// pack two f32 -> two bf16 (RNE) in one VALU instr; bit-identical to f2bf pair.
__device__ __forceinline__ uint32_t f2bf_pk(float lo, float hi) {
    uint32_t r;
    asm("v_cvt_pk_bf16_f32 %0, %1, %2" : "=v"(r) : "v"(lo), "v"(hi));
    return r;
}
__device__ __forceinline__ float bf2f(short s) {
    union { uint32_t u; float f; } v; v.u = ((uint32_t)(uint16_t)s) << 16;
    return v.f;
}
// Scalar activations (IEEE division — R9-proven). Used only in cold paths.
// R13 ERRATUM: __builtin_amdgcn_rcpf substitution produced absmax 0.76 (vs 9.8e-4)
// — categorically wrong results on this toolchain despite 1-ulp spec. Reverted;
// do NOT reintroduce hardware rcp here.
__device__ __forceinline__ float sig_(float x)  { return 1.0f / (1.0f + __expf(-x)); }
__device__ __forceinline__ float tanh_(float x) { return 1.0f - 2.0f / (1.0f + __expf(2.0f * x)); }
__device__ __forceinline__ float silu_(float x) { return x / (1.0f + __expf(-x)); }

// Paired activations sharing ONE IEEE division per pair (the epilogues always
// produce bf16 packs of 2): 1/da = db*inv, 1/db = da*inv with inv = 1/(da*db).
// Replaces 2 divisions (~11 instr each) with 1 division + 3 multiplies.
// Error 1 -> ~3 ulp (1e-7 abs) — invisible under bf16 storage rounding (4e-3).
__device__ __forceinline__ void sig2_(float a, float b, float& sa, float& sb) {
    float da = 1.0f + __expf(-a);
    float db = 1.0f + __expf(-b);
    float inv = 1.0f / (da * db);
    sa = db * inv;
    sb = da * inv;
}
__device__ __forceinline__ void tanh2_(float a, float b, float& ta, float& tb) {
    float da = 1.0f + __expf(2.0f * a);
    float db = 1.0f + __expf(2.0f * b);
    float inv = 1.0f / (da * db);
    ta = 1.0f - 2.0f * (db * inv);
    tb = 1.0f - 2.0f * (da * inv);
}
__device__ __forceinline__ void silu2_(float a, float b, float& sa, float& sb) {
    float da = 1.0f + __expf(-a);
    float db = 1.0f + __expf(-b);
    float inv = 1.0f / (da * db);
    sa = a * (db * inv);
    sb = b * (da * inv);
}

#define MFMA_BF16 __builtin_amdgcn_mfma_f32_16x16x32_bf16

// ---------------- prep: 12 transposed + augmented bf16 weight matrices in ws ------------
// mat m = layer*4 + {0:F,1:U,2:O1,3:O2}; Bt[n][kk]:
//   kk<512 -> U[kk][n]; 512..515 -> W[kk-512][n] (0 for O2); 516 -> bias[n]; else 0.
__global__ void prep_kernel(const float* __restrict__ Wf,  const float* __restrict__ Uf,  const float* __restrict__ bf,
                            const float* __restrict__ Wu,  const float* __restrict__ Uu,  const float* __restrict__ bu,
                            const float* __restrict__ Wo1, const float* __restrict__ Uo1, const float* __restrict__ bo1,
                            const float* __restrict__ Wo2, const float* __restrict__ bo2,
                            short* __restrict__ ws) {
    int idx = blockIdx.x * 256 + threadIdx.x;
    int m   = idx / WELEMS;
    if (m >= 12) return;
    int rem = idx - m * WELEMS;
    int n   = rem / KAUG;
    int kk  = rem - n * KAUG;
    int layer = m >> 2, t = m & 3;
    const float* U; const float* W; const float* b;
    switch (t) {
        case 0:  U = Uf;  W = Wf;      b = bf;  break;
        case 1:  U = Uu;  W = Wu;      b = bu;  break;
        case 2:  U = Uo1; W = Wo1;     b = bo1; break;
        default: U = Wo2; W = nullptr; b = bo2; break;
    }
    float val = 0.0f;
    if (kk < NN)             val = U[layer * NN * NN + kk * NN + n];
    else if (kk < NN + DIN)  val = W ? W[layer * DIN * NN + (kk - NN) * NN + n] : 0.0f;
    else if (kk == NN + DIN) val = b[layer * NN + n];
    ws[idx] = f2bf(val);
}

// 64x32 @ K=544 MFMA block: A from LDS, Bt from global.
// A: distance-1 ping-pong. B: distance-2 rolling prefetch (R4/R9-proven schedule;
// R12 showed d4 is null -> d2 is the depth sweet spot within the 64-arch-VGPR budget).
// Registers: A 32 + B 16 + addr ~12 arch + acc 32 AGPR — fits, no spill.
// 17 K-halves: 7 x 2-half pipelined iters + 3-half static tail (no OOB loads).
__device__ __forceinline__ void mm1(const short* __restrict__ Asrc, const short* __restrict__ Bt,
                                    int n0, int l16, int quad, f32x4 (&acc)[4][2]) {
#pragma unroll
    for (int mt = 0; mt < 4; ++mt)
#pragma unroll
        for (int nt = 0; nt < 2; ++nt) acc[mt][nt] = f32x4{0.f, 0.f, 0.f, 0.f};
    const short* aP = Asrc + l16 * LDA + quad * 8;
    const short* bP = Bt + (size_t)(n0 + l16) * KAUG + quad * 8;

    short8 a0[4], a1[4];
    short8 b0[2], b1[2];

#pragma unroll
    for (int mt = 0; mt < 4; ++mt) a0[mt] = *(const short8*)(aP + mt * 16 * LDA);
#pragma unroll
    for (int nt = 0; nt < 2; ++nt) {
        b0[nt] = *(const short8*)(bP + nt * 16 * KAUG);        // B[0]
        b1[nt] = *(const short8*)(bP + nt * 16 * KAUG + 32);   // B[1]
    }

#pragma unroll 1
    for (int i = 0; i < 7; ++i) {          // halves 2i, 2i+1  (0..13)
#pragma unroll
        for (int mt = 0; mt < 4; ++mt) a1[mt] = *(const short8*)(aP + mt * 16 * LDA + 32);   // A[2i+1]
#pragma unroll
        for (int mt = 0; mt < 4; ++mt) {
            acc[mt][0] = MFMA_BF16(a0[mt], b0[0], acc[mt][0], 0, 0, 0);  // h=2i
            acc[mt][1] = MFMA_BF16(a0[mt], b0[1], acc[mt][1], 0, 0, 0);
        }
#pragma unroll
        for (int nt = 0; nt < 2; ++nt) b0[nt] = *(const short8*)(bP + nt * 16 * KAUG + 64);  // B[2i+2]
#pragma unroll
        for (int mt = 0; mt < 4; ++mt) a0[mt] = *(const short8*)(aP + mt * 16 * LDA + 64);   // A[2i+2]
#pragma unroll
        for (int mt = 0; mt < 4; ++mt) {
            acc[mt][0] = MFMA_BF16(a1[mt], b1[0], acc[mt][0], 0, 0, 0);  // h=2i+1
            acc[mt][1] = MFMA_BF16(a1[mt], b1[1], acc[mt][1], 0, 0, 0);
        }
#pragma unroll
        for (int nt = 0; nt < 2; ++nt) b1[nt] = *(const short8*)(bP + nt * 16 * KAUG + 96);  // B[2i+3]
        aP += 64; bP += 64;
    }
    // tail: halves 14..16; here a0=A[14], b0=B[14], b1=B[15], base advanced to half 14
#pragma unroll
    for (int mt = 0; mt < 4; ++mt) a1[mt] = *(const short8*)(aP + mt * 16 * LDA + 32);       // A[15]
#pragma unroll
    for (int mt = 0; mt < 4; ++mt) {
        acc[mt][0] = MFMA_BF16(a0[mt], b0[0], acc[mt][0], 0, 0, 0);  // h14
        acc[mt][1] = MFMA_BF16(a0[mt], b0[1], acc[mt][1], 0, 0, 0);
    }
#pragma unroll
    for (int nt = 0; nt < 2; ++nt) b0[nt] = *(const short8*)(bP + nt * 16 * KAUG + 64);      // B[16]
#pragma unroll
    for (int mt = 0; mt < 4; ++mt) a0[mt] = *(const short8*)(aP + mt * 16 * LDA + 64);       // A[16]
#pragma unroll
    for (int mt = 0; mt < 4; ++mt) {
        acc[mt][0] = MFMA_BF16(a1[mt], b1[0], acc[mt][0], 0, 0, 0);  // h15
        acc[mt][1] = MFMA_BF16(a1[mt], b1[1], acc[mt][1], 0, 0, 0);
    }
#pragma unroll
    for (int mt = 0; mt < 4; ++mt) {
        acc[mt][0] = MFMA_BF16(a0[mt], b0[0], acc[mt][0], 0, 0, 0);  // h16
        acc[mt][1] = MFMA_BF16(a0[mt], b0[1], acc[mt][1], 0, 0, 0);
    }
}

// ---------------- fused DGM kernel: one 16-wave workgroup = 64 batch rows ----------------
__global__ void __launch_bounds__(NTHREADS, 4)
dgm_kernel(const float* __restrict__ X, const float* __restrict__ W_in, const float* __restrict__ b_in,
           const float* __restrict__ W_out, const float* __restrict__ b_out,
           const short* __restrict__ wmats, float* __restrict__ out) {
    extern __shared__ short lds[];
    short* Hb = lds;                 // [MTILE][LDA]  bf16, cols 512..516 = [X|1]
    short* Tb = lds + MTILE * LDA;   // [MTILE][LDA]  bf16, same augmentation (0,0,0,0,1)

    const int tid  = threadIdx.x;
    const int lane = tid & 63;
    const int wv   = tid >> 6;       // wave 0..15
    const int l16  = lane & 15;
    const int quad = lane >> 4;
    const int n0   = wv * 32;        // this wave's 32-column block
    const int rbase = blockIdx.x * MTILE;

    // ---- H = silu(X @ W_in + b_in): column fixed per thread -> hoist W_in/b_in loads ----
    {
        const int cfix = tid & (NN - 1);
        const int rstart = tid >> 9;             // 0 or 1; rows advance by 2 per j
        const float w0 = W_in[0 * NN + cfix];
        const float w1 = W_in[1 * NN + cfix];
        const float w2 = W_in[2 * NN + cfix];
        const float w3 = W_in[3 * NN + cfix];
        const float bc = b_in[cfix];
#pragma unroll 4
        for (int j = 0; j < (MTILE * NN) / NTHREADS; ++j) {
            int r = rstart + j * (NTHREADS / NN);
            const float4 x = *(const float4*)(X + (size_t)(rbase + r) * DIN);
            float v = bc + x.x * w0 + x.y * w1 + x.z * w2 + x.w * w3;
            Hb[r * LDA + cfix] = f2bf(silu_(v));
        }
    }
    if (tid < MTILE) {
        int r = tid;
        const float* xr = X + (size_t)(rbase + r) * DIN;
#pragma unroll
        for (int k = 0; k < DIN; ++k) {
            Hb[r * LDA + NN + k] = f2bf(xr[k]);
            Tb[r * LDA + NN + k] = 0;
        }
        Hb[r * LDA + NN + DIN] = f2bf(1.0f);
        Tb[r * LDA + NN + DIN] = f2bf(1.0f);
        for (int k = NN + DIN + 1; k < KAUG; ++k) {
            Hb[r * LDA + k] = 0;
            Tb[r * LDA + k] = 0;
        }
    }
    __syncthreads();

    uint32_t Fpack[16];   // sigmoid(F) for this wave's 64x32 tile, packed bf16 pairs

    for (int layer = 0; layer < NLAYERS; ++layer) {
        const short* wF  = wmats + (size_t)(layer * 4 + 0) * WELEMS;
        const short* wU  = wmats + (size_t)(layer * 4 + 1) * WELEMS;
        const short* wO1 = wmats + (size_t)(layer * 4 + 2) * WELEMS;
        const short* wO2 = wmats + (size_t)(layer * 4 + 3) * WELEMS;

        // ---- Phase A: T = sigmoid(pre_U)*tanh(pre_O1) -> Tb; F kept packed in regs ----
        uint32_t Tpack[16];
        {
            f32x4 aO[4][2];
            mm1(Hb, wO1, n0, l16, quad, aO);
#pragma unroll
            for (int mt = 0; mt < 4; ++mt)
#pragma unroll
                for (int nt = 0; nt < 2; ++nt)
#pragma unroll
                    for (int rp = 0; rp < 2; ++rp) {
                        float t0, t1;
                        tanh2_(aO[mt][nt][2 * rp + 0], aO[mt][nt][2 * rp + 1], t0, t1);
                        Tpack[mt * 4 + nt * 2 + rp] = f2bf_pk(t0, t1);
                    }
        }
        {
            f32x4 aU[4][2];
            mm1(Hb, wU, n0, l16, quad, aU);
#pragma unroll
            for (int mt = 0; mt < 4; ++mt)
#pragma unroll
                for (int nt = 0; nt < 2; ++nt)
#pragma unroll
                    for (int rp = 0; rp < 2; ++rp) {
                        uint32_t tp = Tpack[mt * 4 + nt * 2 + rp];
                        float to0 = bf2f((short)(uint16_t)(tp & 0xffffu));
                        float to1 = bf2f((short)(uint16_t)(tp >> 16));
                        float s0, s1;
                        sig2_(aU[mt][nt][2 * rp + 0], aU[mt][nt][2 * rp + 1], s0, s1);
                        uint32_t pk = f2bf_pk(s0 * to0, s1 * to1);
                        int row = mt * 16 + quad * 4 + 2 * rp;
                        int col = n0 + nt * 16 + l16;
                        Tb[row * LDA + col]       = (short)(uint16_t)(pk & 0xffffu);
                        Tb[(row + 1) * LDA + col] = (short)(uint16_t)(pk >> 16);
                    }
        }
        {
            f32x4 aF[4][2];
            mm1(Hb, wF, n0, l16, quad, aF);
#pragma unroll
            for (int mt = 0; mt < 4; ++mt)
#pragma unroll
                for (int nt = 0; nt < 2; ++nt)
#pragma unroll
                    for (int rp = 0; rp < 2; ++rp) {
                        float s0, s1;
                        sig2_(aF[mt][nt][2 * rp + 0], aF[mt][nt][2 * rp + 1], s0, s1);
                        Fpack[mt * 4 + nt * 2 + rp] = f2bf_pk(s0, s1);
                    }
        }
        __syncthreads();   // Tb complete everywhere; Hb reads as A-operand done

        // ---- Phase B: O2 = silu(T @ Wo2 + bo2); H = F*H + O2 (own tile only) ----
        {
            f32x4 aO2[4][2];
            mm1(Tb, wO2, n0, l16, quad, aO2);
#pragma unroll
            for (int mt = 0; mt < 4; ++mt)
#pragma unroll
                for (int nt = 0; nt < 2; ++nt)
#pragma unroll
                    for (int rp = 0; rp < 2; ++rp) {
                        uint32_t fp = Fpack[mt * 4 + nt * 2 + rp];
                        float f0 = bf2f((short)(uint16_t)(fp & 0xffffu));
                        float f1 = bf2f((short)(uint16_t)(fp >> 16));
                        int row = mt * 16 + quad * 4 + 2 * rp;
                        int col = n0 + nt * 16 + l16;
                        float h0 = bf2f(Hb[row * LDA + col]);
                        float h1 = bf2f(Hb[(row + 1) * LDA + col]);
                        float sl0, sl1;
                        silu2_(aO2[mt][nt][2 * rp + 0], aO2[mt][nt][2 * rp + 1], sl0, sl1);
                        uint32_t pk = f2bf_pk(f0 * h0 + sl0, f1 * h1 + sl1);
                        Hb[row * LDA + col]       = (short)(uint16_t)(pk & 0xffffu);
                        Hb[(row + 1) * LDA + col] = (short)(uint16_t)(pk >> 16);
                    }
        }
        __syncthreads();   // Hb fully updated before next layer reads all of it
    }

    // ---- out = silu(H @ W_out + b_out): b128 LDS reads (aligned: LDA*2=1104=69*16) ----
    {
        const int r = tid >> 4, q = tid & 15;
        const int c0 = q * (NN / 16);
        const short8* hp = (const short8*)(Hb + r * LDA + c0);
        float p = 0.0f;
#pragma unroll
        for (int v = 0; v < (NN / 16) / 8; ++v) {
            short8 h = hp[v];
#pragma unroll
            for (int e = 0; e < 8; ++e)
                p += bf2f(h[e]) * W_out[c0 + v * 8 + e];
        }
        float* red = (float*)Tb;     // Tb is free now
        red[tid] = p;
        __syncthreads();
        if (q == 0) {
            float s = b_out[0];
#pragma unroll
            for (int i = 0; i < 16; ++i) s += red[r * 16 + i];
            out[rbase + r] = silu_(s);
        }
    }
}

extern "C" void kernel_launch(void* const* d_in, const int* in_sizes, int n_in,
                              void* d_out, int out_size, void* d_ws, size_t ws_size,
                              hipStream_t stream) {
    const float* X     = (const float*)d_in[0];
    const float* W_in  = (const float*)d_in[1];
    const float* b_in  = (const float*)d_in[2];
    const float* Wf    = (const float*)d_in[3];
    const float* Uf    = (const float*)d_in[4];
    const float* bf    = (const float*)d_in[5];
    const float* Wu    = (const float*)d_in[6];
    const float* Uu    = (const float*)d_in[7];
    const float* bu    = (const float*)d_in[8];
    const float* Wo1   = (const float*)d_in[9];
    const float* Uo1   = (const float*)d_in[10];
    const float* bo1   = (const float*)d_in[11];
    const float* Wo2   = (const float*)d_in[12];
    const float* bo2   = (const float*)d_in[13];
    const float* W_out = (const float*)d_in[14];
    const float* b_out = (const float*)d_in[15];
    float* out = (float*)d_out;
    short* ws  = (short*)d_ws;       // needs 12*512*544*2 = 6.7 MB

    const int B = in_sizes[0] / DIN;

    prep_kernel<<<(12 * WELEMS + 255) / 256, 256, 0, stream>>>(
        Wf, Uf, bf, Wu, Uu, bu, Wo1, Uo1, bo1, Wo2, bo2, ws);

    hipFuncSetAttribute((const void*)dgm_kernel,
                        hipFuncAttributeMaxDynamicSharedMemorySize, LDS_BYTES);
    dgm_kernel<<<B / MTILE, NTHREADS, LDS_BYTES, stream>>>(X, W_in, b_in, W_out, b_out, ws, out);
}

// Round 15
// 1177.266 us; speedup vs baseline: 1.0657x; 1.0164x over previous
//
#include <hip/hip_runtime.h>
#include <cstdint>
#include <cstddef>

#define NLAYERS 3
#define NN      512
#define DIN     4
#define MTILE   64            // batch rows per workgroup
#define KAUG    544           // 512 (H/T) + 4 (X) + 1 (bias one) + 27 zero pad
#define KA      560           // GLOBAL H/T row stride in bf16 elems (1120 B, 16B-aligned)
#define LDA     552           // LDS row stride (fallback fused path)
#define WELEMS  (NN * KAUG)   // one prepared weight matrix, bf16 elems
#define LDS_BYTES (2 * MTILE * LDA * 2)
#define NTHREADS 1024         // 16 waves: one 32-col block per wave -> 4 waves/SIMD

typedef __attribute__((ext_vector_type(8))) short short8;   // 8 x bf16 (4 VGPRs)
typedef __attribute__((ext_vector_type(4))) float f32x4;    // MFMA accumulator

__device__ __forceinline__ short f2bf(float f) {
    union { float f; uint32_t u; } v; v.f = f;
    uint32_t r = v.u + 0x7fffu + ((v.u >> 16) & 1u);   // RNE
    return (short)(r >> 16);
}
__device__ __forceinline__ uint32_t f2bf_pk(float lo, float hi) {
    uint32_t r;
    asm("v_cvt_pk_bf16_f32 %0, %1, %2" : "=v"(r) : "v"(lo), "v"(hi));
    return r;
}
__device__ __forceinline__ float bf2f(short s) {
    union { uint32_t u; float f; } v; v.u = ((uint32_t)(uint16_t)s) << 16;
    return v.f;
}
// R13 ERRATUM: __builtin_amdgcn_rcpf substitution produced absmax 0.76 — do NOT use.
__device__ __forceinline__ float sig_(float x)  { return 1.0f / (1.0f + __expf(-x)); }
__device__ __forceinline__ float tanh_(float x) { return 1.0f - 2.0f / (1.0f + __expf(2.0f * x)); }
__device__ __forceinline__ float silu_(float x) { return x / (1.0f + __expf(-x)); }
// Paired activations: one IEEE division per bf16 pack pair (R14-proven).
__device__ __forceinline__ void sig2_(float a, float b, float& sa, float& sb) {
    float da = 1.0f + __expf(-a);
    float db = 1.0f + __expf(-b);
    float inv = 1.0f / (da * db);
    sa = db * inv; sb = da * inv;
}
__device__ __forceinline__ void tanh2_(float a, float b, float& ta, float& tb) {
    float da = 1.0f + __expf(2.0f * a);
    float db = 1.0f + __expf(2.0f * b);
    float inv = 1.0f / (da * db);
    ta = 1.0f - 2.0f * (db * inv); tb = 1.0f - 2.0f * (da * inv);
}
__device__ __forceinline__ void silu2_(float a, float b, float& sa, float& sb) {
    float da = 1.0f + __expf(-a);
    float db = 1.0f + __expf(-b);
    float inv = 1.0f / (da * db);
    sa = a * (db * inv); sb = b * (da * inv);
}

#define MFMA_BF16 __builtin_amdgcn_mfma_f32_16x16x32_bf16

// ---------------- prep: 12 transposed + augmented bf16 weight matrices in ws ------------
__global__ void prep_kernel(const float* __restrict__ Wf,  const float* __restrict__ Uf,  const float* __restrict__ bf,
                            const float* __restrict__ Wu,  const float* __restrict__ Uu,  const float* __restrict__ bu,
                            const float* __restrict__ Wo1, const float* __restrict__ Uo1, const float* __restrict__ bo1,
                            const float* __restrict__ Wo2, const float* __restrict__ bo2,
                            short* __restrict__ ws) {
    int idx = blockIdx.x * 256 + threadIdx.x;
    int m   = idx / WELEMS;
    if (m >= 12) return;
    int rem = idx - m * WELEMS;
    int n   = rem / KAUG;
    int kk  = rem - n * KAUG;
    int layer = m >> 2, t = m & 3;
    const float* U; const float* W; const float* b;
    switch (t) {
        case 0:  U = Uf;  W = Wf;      b = bf;  break;
        case 1:  U = Uu;  W = Wu;      b = bu;  break;
        case 2:  U = Uo1; W = Wo1;     b = bo1; break;
        default: U = Wo2; W = nullptr; b = bo2; break;
    }
    float val = 0.0f;
    if (kk < NN)             val = U[layer * NN * NN + kk * NN + n];
    else if (kk < NN + DIN)  val = W ? W[layer * DIN * NN + (kk - NN) * NN + n] : 0.0f;
    else if (kk == NN + DIN) val = b[layer * NN + n];
    ws[idx] = f2bf(val);
}

// ================= BARRIER-FREE STREAMING PATH (A from global, no LDS) =================
// Each wave owns a 64x32 output tile; 16 waves/WG cover N=512; waves are fully
// independent (no barriers) so the 4 waves/SIMD self-stagger and decorrelate their
// latency stalls — the lever the fused structure's lockstep blocked (R10/R11).
// A tensors (H, T) are L3-warm (134-147 MB < 256 MB, written by the previous kernel).

// single-B 64x32 @ K=544: A from GLOBAL (stride KA), B from global. R9 schedule
// (A d1 ping-pong + B d2 rolling); regs A 32 + B 16 + addr ~12 <= 64 arch, acc 32 AGPR.
__device__ __forceinline__ void mm1g(const short* __restrict__ Asrc, const short* __restrict__ Bt,
                                     int n0, int l16, int quad, f32x4 (&acc)[4][2]) {
#pragma unroll
    for (int mt = 0; mt < 4; ++mt)
#pragma unroll
        for (int nt = 0; nt < 2; ++nt) acc[mt][nt] = f32x4{0.f, 0.f, 0.f, 0.f};
    const short* aP = Asrc + l16 * KA + quad * 8;
    const short* bP = Bt + (size_t)(n0 + l16) * KAUG + quad * 8;

    short8 a0[4], a1[4];
    short8 b0[2], b1[2];

#pragma unroll
    for (int mt = 0; mt < 4; ++mt) a0[mt] = *(const short8*)(aP + mt * 16 * KA);
#pragma unroll
    for (int nt = 0; nt < 2; ++nt) {
        b0[nt] = *(const short8*)(bP + nt * 16 * KAUG);
        b1[nt] = *(const short8*)(bP + nt * 16 * KAUG + 32);
    }

#pragma unroll 1
    for (int i = 0; i < 7; ++i) {
#pragma unroll
        for (int mt = 0; mt < 4; ++mt) a1[mt] = *(const short8*)(aP + mt * 16 * KA + 32);
#pragma unroll
        for (int mt = 0; mt < 4; ++mt) {
            acc[mt][0] = MFMA_BF16(a0[mt], b0[0], acc[mt][0], 0, 0, 0);
            acc[mt][1] = MFMA_BF16(a0[mt], b0[1], acc[mt][1], 0, 0, 0);
        }
#pragma unroll
        for (int nt = 0; nt < 2; ++nt) b0[nt] = *(const short8*)(bP + nt * 16 * KAUG + 64);
#pragma unroll
        for (int mt = 0; mt < 4; ++mt) a0[mt] = *(const short8*)(aP + mt * 16 * KA + 64);
#pragma unroll
        for (int mt = 0; mt < 4; ++mt) {
            acc[mt][0] = MFMA_BF16(a1[mt], b1[0], acc[mt][0], 0, 0, 0);
            acc[mt][1] = MFMA_BF16(a1[mt], b1[1], acc[mt][1], 0, 0, 0);
        }
#pragma unroll
        for (int nt = 0; nt < 2; ++nt) b1[nt] = *(const short8*)(bP + nt * 16 * KAUG + 96);
        aP += 64; bP += 64;
    }
#pragma unroll
    for (int mt = 0; mt < 4; ++mt) a1[mt] = *(const short8*)(aP + mt * 16 * KA + 32);
#pragma unroll
    for (int mt = 0; mt < 4; ++mt) {
        acc[mt][0] = MFMA_BF16(a0[mt], b0[0], acc[mt][0], 0, 0, 0);
        acc[mt][1] = MFMA_BF16(a0[mt], b0[1], acc[mt][1], 0, 0, 0);
    }
#pragma unroll
    for (int nt = 0; nt < 2; ++nt) b0[nt] = *(const short8*)(bP + nt * 16 * KAUG + 64);
#pragma unroll
    for (int mt = 0; mt < 4; ++mt) a0[mt] = *(const short8*)(aP + mt * 16 * KA + 64);
#pragma unroll
    for (int mt = 0; mt < 4; ++mt) {
        acc[mt][0] = MFMA_BF16(a1[mt], b1[0], acc[mt][0], 0, 0, 0);
        acc[mt][1] = MFMA_BF16(a1[mt], b1[1], acc[mt][1], 0, 0, 0);
    }
#pragma unroll
    for (int mt = 0; mt < 4; ++mt) {
        acc[mt][0] = MFMA_BF16(a0[mt], b0[0], acc[mt][0], 0, 0, 0);
        acc[mt][1] = MFMA_BF16(a0[mt], b0[1], acc[mt][1], 0, 0, 0);
    }
}

// dual-B (U and O1 share every A fragment): R5-proven schedule, A from GLOBAL.
// Regs: accU 32 + accO 32 (AGPR) + A rotate 16 + B 2x16 + addr ~10 arch.
__device__ __forceinline__ void mmUO1g(const short* __restrict__ Asrc,
                                       const short* __restrict__ BtU, const short* __restrict__ BtO,
                                       int n0, int l16, int quad,
                                       f32x4 (&accU)[4][2], f32x4 (&accO)[4][2]) {
#pragma unroll
    for (int mt = 0; mt < 4; ++mt)
#pragma unroll
        for (int nt = 0; nt < 2; ++nt) {
            accU[mt][nt] = f32x4{0.f, 0.f, 0.f, 0.f};
            accO[mt][nt] = f32x4{0.f, 0.f, 0.f, 0.f};
        }
    const short* aP  = Asrc + l16 * KA + quad * 8;
    const short* bUP = BtU + (size_t)(n0 + l16) * KAUG + quad * 8;
    const short* bOP = BtO + (size_t)(n0 + l16) * KAUG + quad * 8;

    short8 a[4];
    short8 bU0[2], bU1[2], bO0[2], bO1[2];

#pragma unroll
    for (int mt = 0; mt < 4; ++mt) a[mt] = *(const short8*)(aP + mt * 16 * KA);   // A[0]
#pragma unroll
    for (int nt = 0; nt < 2; ++nt) {
        bU0[nt] = *(const short8*)(bUP + nt * 16 * KAUG);
        bU1[nt] = *(const short8*)(bUP + nt * 16 * KAUG + 32);
        bO0[nt] = *(const short8*)(bOP + nt * 16 * KAUG);
        bO1[nt] = *(const short8*)(bOP + nt * 16 * KAUG + 32);
    }

#pragma unroll 1
    for (int i = 0; i < 8; ++i) {          // halves 2i, 2i+1  (0..15)
#pragma unroll
        for (int mt = 0; mt < 4; ++mt) {
            accU[mt][0] = MFMA_BF16(a[mt], bU0[0], accU[mt][0], 0, 0, 0);
            accU[mt][1] = MFMA_BF16(a[mt], bU0[1], accU[mt][1], 0, 0, 0);
            accO[mt][0] = MFMA_BF16(a[mt], bO0[0], accO[mt][0], 0, 0, 0);
            accO[mt][1] = MFMA_BF16(a[mt], bO0[1], accO[mt][1], 0, 0, 0);
            a[mt] = *(const short8*)(aP + mt * 16 * KA + 32);   // A[2i+1]
        }
#pragma unroll
        for (int nt = 0; nt < 2; ++nt) {
            bU0[nt] = *(const short8*)(bUP + nt * 16 * KAUG + 64);  // B[2i+2]
            bO0[nt] = *(const short8*)(bOP + nt * 16 * KAUG + 64);
        }
#pragma unroll
        for (int mt = 0; mt < 4; ++mt) {
            accU[mt][0] = MFMA_BF16(a[mt], bU1[0], accU[mt][0], 0, 0, 0);
            accU[mt][1] = MFMA_BF16(a[mt], bU1[1], accU[mt][1], 0, 0, 0);
            accO[mt][0] = MFMA_BF16(a[mt], bO1[0], accO[mt][0], 0, 0, 0);
            accO[mt][1] = MFMA_BF16(a[mt], bO1[1], accO[mt][1], 0, 0, 0);
            a[mt] = *(const short8*)(aP + mt * 16 * KA + 64);   // A[2i+2]
        }
#pragma unroll
        for (int nt = 0; nt < 2; ++nt) {
            bU1[nt] = *(const short8*)(bUP + nt * 16 * KAUG + 96);  // B[2i+3]
            bO1[nt] = *(const short8*)(bOP + nt * 16 * KAUG + 96);
        }
        aP += 64; bUP += 64; bOP += 64;
    }
    // tail: half 16; a[] = A[16], bU0/bO0 = B[16]
#pragma unroll
    for (int mt = 0; mt < 4; ++mt) {
        accU[mt][0] = MFMA_BF16(a[mt], bU0[0], accU[mt][0], 0, 0, 0);
        accU[mt][1] = MFMA_BF16(a[mt], bU0[1], accU[mt][1], 0, 0, 0);
        accO[mt][0] = MFMA_BF16(a[mt], bO0[0], accO[mt][0], 0, 0, 0);
        accO[mt][1] = MFMA_BF16(a[mt], bO0[1], accO[mt][1], 0, 0, 0);
    }
}

// ---- H-init: H_g = silu(X @ W_in + b_in) with aug cols [X|1|0..]; T_g aug [0,0,0,0,1,0..]
__global__ void __launch_bounds__(NTHREADS)
hinit_kernel(const float* __restrict__ X, const float* __restrict__ W_in, const float* __restrict__ b_in,
             short* __restrict__ Hg, short* __restrict__ Tg) {
    const int tid = threadIdx.x;
    const int rbase = blockIdx.x * MTILE;
    {
        const int cfix = tid & (NN - 1);
        const int rstart = tid >> 9;
        const float w0 = W_in[0 * NN + cfix];
        const float w1 = W_in[1 * NN + cfix];
        const float w2 = W_in[2 * NN + cfix];
        const float w3 = W_in[3 * NN + cfix];
        const float bc = b_in[cfix];
#pragma unroll 4
        for (int j = 0; j < (MTILE * NN) / NTHREADS; ++j) {
            int r = rstart + j * (NTHREADS / NN);
            const float4 x = *(const float4*)(X + (size_t)(rbase + r) * DIN);
            float v = bc + x.x * w0 + x.y * w1 + x.z * w2 + x.w * w3;
            Hg[(size_t)(rbase + r) * KA + cfix] = f2bf(silu_(v));
        }
    }
    if (tid < MTILE) {
        int r = rbase + tid;
        const float* xr = X + (size_t)r * DIN;
#pragma unroll
        for (int k = 0; k < DIN; ++k) {
            Hg[(size_t)r * KA + NN + k] = f2bf(xr[k]);
            Tg[(size_t)r * KA + NN + k] = 0;
        }
        Hg[(size_t)r * KA + NN + DIN] = f2bf(1.0f);
        Tg[(size_t)r * KA + NN + DIN] = f2bf(1.0f);
        for (int k = NN + DIN + 1; k < KAUG; ++k) {   // cols 517..543 (read by K-loop)
            Hg[(size_t)r * KA + k] = 0;
            Tg[(size_t)r * KA + k] = 0;
        }
    }
}

// ---- T = sigmoid(H@U) * tanh(H@O1)  (dual-stream, barrier-free) ----
__global__ void __launch_bounds__(NTHREADS, 4)
gemm_t_kernel(const short* __restrict__ Hg, const short* __restrict__ wU, const short* __restrict__ wO1,
              short* __restrict__ Tg) {
    const int tid  = threadIdx.x;
    const int lane = tid & 63;
    const int wv   = tid >> 6;
    const int l16  = lane & 15;
    const int quad = lane >> 4;
    const int n0   = wv * 32;
    const int rbase = blockIdx.x * MTILE;

    f32x4 aU[4][2], aO[4][2];
    mmUO1g(Hg + (size_t)rbase * KA, wU, wO1, n0, l16, quad, aU, aO);
#pragma unroll
    for (int mt = 0; mt < 4; ++mt)
#pragma unroll
        for (int nt = 0; nt < 2; ++nt)
#pragma unroll
            for (int rp = 0; rp < 2; ++rp) {
                float t0, t1, s0, s1;
                tanh2_(aO[mt][nt][2 * rp + 0], aO[mt][nt][2 * rp + 1], t0, t1);
                sig2_(aU[mt][nt][2 * rp + 0], aU[mt][nt][2 * rp + 1], s0, s1);
                uint32_t pk = f2bf_pk(s0 * t0, s1 * t1);
                int row = rbase + mt * 16 + quad * 4 + 2 * rp;
                int col = n0 + nt * 16 + l16;
                Tg[(size_t)row * KA + col]       = (short)(uint16_t)(pk & 0xffffu);
                Tg[(size_t)(row + 1) * KA + col] = (short)(uint16_t)(pk >> 16);
            }
}

// ---- Fs = sigmoid(H@F)  (compact [M][NN] layout) ----
__global__ void __launch_bounds__(NTHREADS, 4)
gemm_f_kernel(const short* __restrict__ Hg, const short* __restrict__ wF, short* __restrict__ Fg) {
    const int tid  = threadIdx.x;
    const int lane = tid & 63;
    const int wv   = tid >> 6;
    const int l16  = lane & 15;
    const int quad = lane >> 4;
    const int n0   = wv * 32;
    const int rbase = blockIdx.x * MTILE;

    f32x4 aF[4][2];
    mm1g(Hg + (size_t)rbase * KA, wF, n0, l16, quad, aF);
#pragma unroll
    for (int mt = 0; mt < 4; ++mt)
#pragma unroll
        for (int nt = 0; nt < 2; ++nt)
#pragma unroll
            for (int rp = 0; rp < 2; ++rp) {
                float s0, s1;
                sig2_(aF[mt][nt][2 * rp + 0], aF[mt][nt][2 * rp + 1], s0, s1);
                uint32_t pk = f2bf_pk(s0, s1);
                int row = rbase + mt * 16 + quad * 4 + 2 * rp;
                int col = n0 + nt * 16 + l16;
                Fg[(size_t)row * NN + col]       = (short)(uint16_t)(pk & 0xffffu);
                Fg[(size_t)(row + 1) * NN + col] = (short)(uint16_t)(pk >> 16);
            }
}

// ---- H = Fs*H + silu(T@O2)  (reads Fs, H; writes H cols 0..511) ----
__global__ void __launch_bounds__(NTHREADS, 4)
gemm_h_kernel(const short* __restrict__ Tg, const short* __restrict__ wO2,
              const short* __restrict__ Fg, short* __restrict__ Hg) {
    const int tid  = threadIdx.x;
    const int lane = tid & 63;
    const int wv   = tid >> 6;
    const int l16  = lane & 15;
    const int quad = lane >> 4;
    const int n0   = wv * 32;
    const int rbase = blockIdx.x * MTILE;

    f32x4 aO2[4][2];
    mm1g(Tg + (size_t)rbase * KA, wO2, n0, l16, quad, aO2);
#pragma unroll
    for (int mt = 0; mt < 4; ++mt)
#pragma unroll
        for (int nt = 0; nt < 2; ++nt)
#pragma unroll
            for (int rp = 0; rp < 2; ++rp) {
                int row = rbase + mt * 16 + quad * 4 + 2 * rp;
                int col = n0 + nt * 16 + l16;
                float f0 = bf2f(Fg[(size_t)row * NN + col]);
                float f1 = bf2f(Fg[(size_t)(row + 1) * NN + col]);
                float h0 = bf2f(Hg[(size_t)row * KA + col]);
                float h1 = bf2f(Hg[(size_t)(row + 1) * KA + col]);
                float sl0, sl1;
                silu2_(aO2[mt][nt][2 * rp + 0], aO2[mt][nt][2 * rp + 1], sl0, sl1);
                uint32_t pk = f2bf_pk(f0 * h0 + sl0, f1 * h1 + sl1);
                Hg[(size_t)row * KA + col]       = (short)(uint16_t)(pk & 0xffffu);
                Hg[(size_t)(row + 1) * KA + col] = (short)(uint16_t)(pk >> 16);
            }
}

// ---- out = silu(H @ W_out + b_out): 16 threads per row, coalesced short8 reads ----
__global__ void __launch_bounds__(NTHREADS)
out_kernel(const short* __restrict__ Hg, const float* __restrict__ W_out, const float* __restrict__ b_out,
           float* __restrict__ outp) {
    const int tid = threadIdx.x;
    const int q = tid & 15;
    const int row = blockIdx.x * MTILE + (tid >> 4);
    const short8* hp = (const short8*)(Hg + (size_t)row * KA + q * 32);
    float p = 0.0f;
#pragma unroll
    for (int v = 0; v < 4; ++v) {
        short8 h = hp[v];
#pragma unroll
        for (int e = 0; e < 8; ++e)
            p += bf2f(h[e]) * W_out[q * 32 + v * 8 + e];
    }
    p += __shfl_xor(p, 8, 16);
    p += __shfl_xor(p, 4, 16);
    p += __shfl_xor(p, 2, 16);
    p += __shfl_xor(p, 1, 16);
    if (q == 0) outp[row] = silu_(p + b_out[0]);
}

// ================= FALLBACK: R14 fused kernel (proven 1197 us) =================
__device__ __forceinline__ void mm1(const short* __restrict__ Asrc, const short* __restrict__ Bt,
                                    int n0, int l16, int quad, f32x4 (&acc)[4][2]) {
#pragma unroll
    for (int mt = 0; mt < 4; ++mt)
#pragma unroll
        for (int nt = 0; nt < 2; ++nt) acc[mt][nt] = f32x4{0.f, 0.f, 0.f, 0.f};
    const short* aP = Asrc + l16 * LDA + quad * 8;
    const short* bP = Bt + (size_t)(n0 + l16) * KAUG + quad * 8;

    short8 a0[4], a1[4];
    short8 b0[2], b1[2];

#pragma unroll
    for (int mt = 0; mt < 4; ++mt) a0[mt] = *(const short8*)(aP + mt * 16 * LDA);
#pragma unroll
    for (int nt = 0; nt < 2; ++nt) {
        b0[nt] = *(const short8*)(bP + nt * 16 * KAUG);
        b1[nt] = *(const short8*)(bP + nt * 16 * KAUG + 32);
    }

#pragma unroll 1
    for (int i = 0; i < 7; ++i) {
#pragma unroll
        for (int mt = 0; mt < 4; ++mt) a1[mt] = *(const short8*)(aP + mt * 16 * LDA + 32);
#pragma unroll
        for (int mt = 0; mt < 4; ++mt) {
            acc[mt][0] = MFMA_BF16(a0[mt], b0[0], acc[mt][0], 0, 0, 0);
            acc[mt][1] = MFMA_BF16(a0[mt], b0[1], acc[mt][1], 0, 0, 0);
        }
#pragma unroll
        for (int nt = 0; nt < 2; ++nt) b0[nt] = *(const short8*)(bP + nt * 16 * KAUG + 64);
#pragma unroll
        for (int mt = 0; mt < 4; ++mt) a0[mt] = *(const short8*)(aP + mt * 16 * LDA + 64);
#pragma unroll
        for (int mt = 0; mt < 4; ++mt) {
            acc[mt][0] = MFMA_BF16(a1[mt], b1[0], acc[mt][0], 0, 0, 0);
            acc[mt][1] = MFMA_BF16(a1[mt], b1[1], acc[mt][1], 0, 0, 0);
        }
#pragma unroll
        for (int nt = 0; nt < 2; ++nt) b1[nt] = *(const short8*)(bP + nt * 16 * KAUG + 96);
        aP += 64; bP += 64;
    }
#pragma unroll
    for (int mt = 0; mt < 4; ++mt) a1[mt] = *(const short8*)(aP + mt * 16 * LDA + 32);
#pragma unroll
    for (int mt = 0; mt < 4; ++mt) {
        acc[mt][0] = MFMA_BF16(a0[mt], b0[0], acc[mt][0], 0, 0, 0);
        acc[mt][1] = MFMA_BF16(a0[mt], b0[1], acc[mt][1], 0, 0, 0);
    }
#pragma unroll
    for (int nt = 0; nt < 2; ++nt) b0[nt] = *(const short8*)(bP + nt * 16 * KAUG + 64);
#pragma unroll
    for (int mt = 0; mt < 4; ++mt) a0[mt] = *(const short8*)(aP + mt * 16 * LDA + 64);
#pragma unroll
    for (int mt = 0; mt < 4; ++mt) {
        acc[mt][0] = MFMA_BF16(a1[mt], b1[0], acc[mt][0], 0, 0, 0);
        acc[mt][1] = MFMA_BF16(a1[mt], b1[1], acc[mt][1], 0, 0, 0);
    }
#pragma unroll
    for (int mt = 0; mt < 4; ++mt) {
        acc[mt][0] = MFMA_BF16(a0[mt], b0[0], acc[mt][0], 0, 0, 0);
        acc[mt][1] = MFMA_BF16(a0[mt], b0[1], acc[mt][1], 0, 0, 0);
    }
}

__global__ void __launch_bounds__(NTHREADS, 4)
dgm_kernel(const float* __restrict__ X, const float* __restrict__ W_in, const float* __restrict__ b_in,
           const float* __restrict__ W_out, const float* __restrict__ b_out,
           const short* __restrict__ wmats, float* __restrict__ out) {
    extern __shared__ short lds[];
    short* Hb = lds;
    short* Tb = lds + MTILE * LDA;

    const int tid  = threadIdx.x;
    const int lane = tid & 63;
    const int wv   = tid >> 6;
    const int l16  = lane & 15;
    const int quad = lane >> 4;
    const int n0   = wv * 32;
    const int rbase = blockIdx.x * MTILE;

    {
        const int cfix = tid & (NN - 1);
        const int rstart = tid >> 9;
        const float w0 = W_in[0 * NN + cfix];
        const float w1 = W_in[1 * NN + cfix];
        const float w2 = W_in[2 * NN + cfix];
        const float w3 = W_in[3 * NN + cfix];
        const float bc = b_in[cfix];
#pragma unroll 4
        for (int j = 0; j < (MTILE * NN) / NTHREADS; ++j) {
            int r = rstart + j * (NTHREADS / NN);
            const float4 x = *(const float4*)(X + (size_t)(rbase + r) * DIN);
            float v = bc + x.x * w0 + x.y * w1 + x.z * w2 + x.w * w3;
            Hb[r * LDA + cfix] = f2bf(silu_(v));
        }
    }
    if (tid < MTILE) {
        int r = tid;
        const float* xr = X + (size_t)(rbase + r) * DIN;
#pragma unroll
        for (int k = 0; k < DIN; ++k) {
            Hb[r * LDA + NN + k] = f2bf(xr[k]);
            Tb[r * LDA + NN + k] = 0;
        }
        Hb[r * LDA + NN + DIN] = f2bf(1.0f);
        Tb[r * LDA + NN + DIN] = f2bf(1.0f);
        for (int k = NN + DIN + 1; k < KAUG; ++k) {
            Hb[r * LDA + k] = 0;
            Tb[r * LDA + k] = 0;
        }
    }
    __syncthreads();

    uint32_t Fpack[16];

    for (int layer = 0; layer < NLAYERS; ++layer) {
        const short* wF  = wmats + (size_t)(layer * 4 + 0) * WELEMS;
        const short* wU  = wmats + (size_t)(layer * 4 + 1) * WELEMS;
        const short* wO1 = wmats + (size_t)(layer * 4 + 2) * WELEMS;
        const short* wO2 = wmats + (size_t)(layer * 4 + 3) * WELEMS;

        uint32_t Tpack[16];
        {
            f32x4 aO[4][2];
            mm1(Hb, wO1, n0, l16, quad, aO);
#pragma unroll
            for (int mt = 0; mt < 4; ++mt)
#pragma unroll
                for (int nt = 0; nt < 2; ++nt)
#pragma unroll
                    for (int rp = 0; rp < 2; ++rp) {
                        float t0, t1;
                        tanh2_(aO[mt][nt][2 * rp + 0], aO[mt][nt][2 * rp + 1], t0, t1);
                        Tpack[mt * 4 + nt * 2 + rp] = f2bf_pk(t0, t1);
                    }
        }
        {
            f32x4 aU[4][2];
            mm1(Hb, wU, n0, l16, quad, aU);
#pragma unroll
            for (int mt = 0; mt < 4; ++mt)
#pragma unroll
                for (int nt = 0; nt < 2; ++nt)
#pragma unroll
                    for (int rp = 0; rp < 2; ++rp) {
                        uint32_t tp = Tpack[mt * 4 + nt * 2 + rp];
                        float to0 = bf2f((short)(uint16_t)(tp & 0xffffu));
                        float to1 = bf2f((short)(uint16_t)(tp >> 16));
                        float s0, s1;
                        sig2_(aU[mt][nt][2 * rp + 0], aU[mt][nt][2 * rp + 1], s0, s1);
                        uint32_t pk = f2bf_pk(s0 * to0, s1 * to1);
                        int row = mt * 16 + quad * 4 + 2 * rp;
                        int col = n0 + nt * 16 + l16;
                        Tb[row * LDA + col]       = (short)(uint16_t)(pk & 0xffffu);
                        Tb[(row + 1) * LDA + col] = (short)(uint16_t)(pk >> 16);
                    }
        }
        {
            f32x4 aF[4][2];
            mm1(Hb, wF, n0, l16, quad, aF);
#pragma unroll
            for (int mt = 0; mt < 4; ++mt)
#pragma unroll
                for (int nt = 0; nt < 2; ++nt)
#pragma unroll
                    for (int rp = 0; rp < 2; ++rp) {
                        float s0, s1;
                        sig2_(aF[mt][nt][2 * rp + 0], aF[mt][nt][2 * rp + 1], s0, s1);
                        Fpack[mt * 4 + nt * 2 + rp] = f2bf_pk(s0, s1);
                    }
        }
        __syncthreads();

        {
            f32x4 aO2[4][2];
            mm1(Tb, wO2, n0, l16, quad, aO2);
#pragma unroll
            for (int mt = 0; mt < 4; ++mt)
#pragma unroll
                for (int nt = 0; nt < 2; ++nt)
#pragma unroll
                    for (int rp = 0; rp < 2; ++rp) {
                        uint32_t fp = Fpack[mt * 4 + nt * 2 + rp];
                        float f0 = bf2f((short)(uint16_t)(fp & 0xffffu));
                        float f1 = bf2f((short)(uint16_t)(fp >> 16));
                        int row = mt * 16 + quad * 4 + 2 * rp;
                        int col = n0 + nt * 16 + l16;
                        float h0 = bf2f(Hb[row * LDA + col]);
                        float h1 = bf2f(Hb[(row + 1) * LDA + col]);
                        float sl0, sl1;
                        silu2_(aO2[mt][nt][2 * rp + 0], aO2[mt][nt][2 * rp + 1], sl0, sl1);
                        uint32_t pk = f2bf_pk(f0 * h0 + sl0, f1 * h1 + sl1);
                        Hb[row * LDA + col]       = (short)(uint16_t)(pk & 0xffffu);
                        Hb[(row + 1) * LDA + col] = (short)(uint16_t)(pk >> 16);
                    }
        }
        __syncthreads();
    }

    {
        const int r = tid >> 4, q = tid & 15;
        const int c0 = q * (NN / 16);
        const short8* hp = (const short8*)(Hb + r * LDA + c0);
        float p = 0.0f;
#pragma unroll
        for (int v = 0; v < (NN / 16) / 8; ++v) {
            short8 h = hp[v];
#pragma unroll
            for (int e = 0; e < 8; ++e)
                p += bf2f(h[e]) * W_out[c0 + v * 8 + e];
        }
        float* red = (float*)Tb;
        red[tid] = p;
        __syncthreads();
        if (q == 0) {
            float s = b_out[0];
#pragma unroll
            for (int i = 0; i < 16; ++i) s += red[r * 16 + i];
            out[rbase + r] = silu_(s);
        }
    }
}

extern "C" void kernel_launch(void* const* d_in, const int* in_sizes, int n_in,
                              void* d_out, int out_size, void* d_ws, size_t ws_size,
                              hipStream_t stream) {
    const float* X     = (const float*)d_in[0];
    const float* W_in  = (const float*)d_in[1];
    const float* b_in  = (const float*)d_in[2];
    const float* Wf    = (const float*)d_in[3];
    const float* Uf    = (const float*)d_in[4];
    const float* bf    = (const float*)d_in[5];
    const float* Wu    = (const float*)d_in[6];
    const float* Uu    = (const float*)d_in[7];
    const float* bu    = (const float*)d_in[8];
    const float* Wo1   = (const float*)d_in[9];
    const float* Uo1   = (const float*)d_in[10];
    const float* bo1   = (const float*)d_in[11];
    const float* Wo2   = (const float*)d_in[12];
    const float* bo2   = (const float*)d_in[13];
    const float* W_out = (const float*)d_in[14];
    const float* b_out = (const float*)d_in[15];
    float* out = (float*)d_out;
    short* ws  = (short*)d_ws;

    const int B = in_sizes[0] / DIN;

    prep_kernel<<<(12 * WELEMS + 255) / 256, 256, 0, stream>>>(
        Wf, Uf, bf, Wu, Uu, bu, Wo1, Uo1, bo1, Wo2, bo2, ws);

    // Workspace plan for the barrier-free path:
    //   [wmats 12xWELEMS][H_g BxKA][T_g BxKA][F_g BxNN]  (all bf16)
    const size_t need = 2ull * (12ull * WELEMS + 2ull * (size_t)B * KA + (size_t)B * NN);

    if (ws_size >= need && (B % MTILE) == 0) {
        short* Hg = ws + 12ull * WELEMS;
        short* Tg = Hg + (size_t)B * KA;
        short* Fg = Tg + (size_t)B * KA;
        const int G = B / MTILE;

        hinit_kernel<<<G, NTHREADS, 0, stream>>>(X, W_in, b_in, Hg, Tg);
        for (int layer = 0; layer < NLAYERS; ++layer) {
            const short* wF  = ws + (size_t)(layer * 4 + 0) * WELEMS;
            const short* wU  = ws + (size_t)(layer * 4 + 1) * WELEMS;
            const short* wO1 = ws + (size_t)(layer * 4 + 2) * WELEMS;
            const short* wO2 = ws + (size_t)(layer * 4 + 3) * WELEMS;
            gemm_t_kernel<<<G, NTHREADS, 0, stream>>>(Hg, wU, wO1, Tg);
            gemm_f_kernel<<<G, NTHREADS, 0, stream>>>(Hg, wF, Fg);
            gemm_h_kernel<<<G, NTHREADS, 0, stream>>>(Tg, wO2, Fg, Hg);
        }
        out_kernel<<<G, NTHREADS, 0, stream>>>(Hg, W_out, b_out, out);
    } else {
        // Fallback: proven fused kernel (R14, 1197 us)
        hipFuncSetAttribute((const void*)dgm_kernel,
                            hipFuncAttributeMaxDynamicSharedMemorySize, LDS_BYTES);
        dgm_kernel<<<B / MTILE, NTHREADS, LDS_BYTES, stream>>>(X, W_in, b_in, W_out, b_out, ws, out);
    }
}